// Round 5
// baseline (250.391 us; speedup 1.0000x reference)
//
#include <hip/hip_runtime.h>
#include <hip/hip_bf16.h>

#define BATCH 2
#define SLEN 2048
#define NH 12
#define DM 768
#define DH 64
#define ROWS (BATCH*SLEN)   // 4096
#define NQKV (3*DM)         // 2304
#define NCHUNK 80           // split-K chunks per bh (chunk = up to 8 k-tiles)

typedef __attribute__((ext_vector_type(8))) short bf16x8;
typedef __attribute__((ext_vector_type(4))) float f32x4;
typedef unsigned short u16;
typedef unsigned int u32;
typedef __attribute__((ext_vector_type(4))) unsigned short u16x4;
typedef __attribute__((ext_vector_type(8))) unsigned short u16x8;

__device__ __forceinline__ u16 f2b(float f) {
    unsigned int u = __builtin_bit_cast(unsigned int, f);
    unsigned int r = (u + 0x7FFFu + ((u >> 16) & 1u)) >> 16;
    return (u16)r;
}
__device__ __forceinline__ float b2f(u16 v) {
    unsigned int u = ((unsigned int)v) << 16;
    return __builtin_bit_cast(float, u);
}

// ---------------- pack kernels ----------------

__global__ __launch_bounds__(256) void pack_x(const float* __restrict__ x, u16* __restrict__ xb) {
    int i = blockIdx.x * 256 + threadIdx.x;
    const float4* xv = (const float4*)x;
    float4 a = xv[i * 2], b = xv[i * 2 + 1];
    u16x8 o;
    o[0] = f2b(a.x); o[1] = f2b(a.y); o[2] = f2b(a.z); o[3] = f2b(a.w);
    o[4] = f2b(b.x); o[5] = f2b(b.y); o[6] = f2b(b.z); o[7] = f2b(b.w);
    *(u16x8*)(xb + (size_t)i * 8) = o;
}

__global__ __launch_bounds__(256) void pack_wqkv(const float* __restrict__ WQ, const float* __restrict__ WK,
                                                 const float* __restrict__ WV, u16* __restrict__ out) {
    __shared__ u16 L[64 * 72];
    int mt = blockIdx.x, h = blockIdx.y, sel = blockIdx.z;
    const float* W = sel == 0 ? WQ : (sel == 1 ? WK : WV);
    const float* src = W + ((size_t)h * DM + mt * 64) * DH;
    int t = threadIdx.x;
    for (int j = 0; j < 4; j++) {
        int i = t + 256 * j;
        int r = i >> 4, cf = i & 15;
        float4 v = ((const float4*)src)[i];
        u16x4 o; o[0] = f2b(v.x); o[1] = f2b(v.y); o[2] = f2b(v.z); o[3] = f2b(v.w);
        *(u16x4*)&L[r * 72 + cf * 4] = o;
    }
    __syncthreads();
    u16* orow = out + ((size_t)(sel * DM + h * DH)) * DM + mt * 64;
    for (int j = 0; j < 16; j++) {
        int e = t + 256 * j;
        int d = e >> 6, mm = e & 63;
        orow[(size_t)d * DM + mm] = L[mm * 72 + d];
    }
}

__global__ __launch_bounds__(256) void pack_wo(const float* __restrict__ WO, u16* __restrict__ out) {
    __shared__ u16 L[64 * 72];
    int bi = blockIdx.x, bj = blockIdx.y;
    int t = threadIdx.x;
    for (int j = 0; j < 4; j++) {
        int i = t + 256 * j;
        int r = i >> 4, cf = i & 15;
        float4 v = ((const float4*)(WO + (size_t)(bi * 64 + r) * DM + bj * 64))[cf];
        u16x4 o; o[0] = f2b(v.x); o[1] = f2b(v.y); o[2] = f2b(v.z); o[3] = f2b(v.w);
        *(u16x4*)&L[r * 72 + cf * 4] = o;
    }
    __syncthreads();
    for (int j = 0; j < 16; j++) {
        int e = t + 256 * j;
        int c = e >> 6, r = e & 63;
        out[(size_t)(bj * 64 + c) * DM + bi * 64 + r] = L[r * 72 + c];
    }
}

// ---------------- QKV GEMM (128x96 tile, register-preload pipeline) ----------------
// -> Q(pre-scaled by 0.125*log2e)/K [b,h,s,d], V^T [b,h,d,s]

__global__ __launch_bounds__(256) void gemm_qkv(const u16* __restrict__ A, const u16* __restrict__ Bt,
                                                const float* __restrict__ bQ, const float* __restrict__ bK,
                                                const float* __restrict__ bV,
                                                u16* __restrict__ Qb, u16* __restrict__ Kb, u16* __restrict__ Vb) {
    __shared__ u16 Al[128 * 72];
    __shared__ u16 Bl[96 * 72];
    int t = threadIdx.x;
    int n0 = blockIdx.x * 96, m0 = blockIdx.y * 128;
    int lane = t & 63, w = t >> 6;
    int ln = lane & 15, qd = lane >> 4;
    int wr = (w & 1) * 64, wc = (w >> 1) * 48;
    int sr = t >> 3, scf = t & 7;        // staging: 32 rows x 8 chunks per 256-thr pass
    f32x4 acc[4][3] = {};

    float4 ar[4], br[3];
    auto preload = [&](int kt) {
        const u16* Ap = A + (size_t)m0 * DM + kt * 64;
        const u16* Bp = Bt + (size_t)n0 * DM + kt * 64;
        for (int j = 0; j < 4; j++)
            ar[j] = *(const float4*)(Ap + (size_t)(sr + 32 * j) * DM + scf * 8);
        for (int j = 0; j < 3; j++)
            br[j] = *(const float4*)(Bp + (size_t)(sr + 32 * j) * DM + scf * 8);
    };
    preload(0);

    for (int kt = 0; kt < DM / 64; kt++) {
        __syncthreads();
        for (int j = 0; j < 4; j++)
            *(float4*)&Al[(sr + 32 * j) * 72 + scf * 8] = ar[j];
        for (int j = 0; j < 3; j++)
            *(float4*)&Bl[(sr + 32 * j) * 72 + scf * 8] = br[j];
        __syncthreads();
        if (kt + 1 < DM / 64) preload(kt + 1);
        for (int ks = 0; ks < 2; ks++) {
            bf16x8 af[4], bfr[3];
            for (int rt = 0; rt < 4; rt++)
                af[rt] = *(const bf16x8*)&Al[(wr + rt * 16 + ln) * 72 + ks * 32 + qd * 8];
            for (int ct = 0; ct < 3; ct++)
                bfr[ct] = *(const bf16x8*)&Bl[(wc + ct * 16 + ln) * 72 + ks * 32 + qd * 8];
            for (int rt = 0; rt < 4; rt++)
                for (int ct = 0; ct < 3; ct++)
                    acc[rt][ct] = __builtin_amdgcn_mfma_f32_16x16x32_bf16(af[rt], bfr[ct], acc[rt][ct], 0, 0, 0);
        }
    }
    int sel = n0 / DM;                   // 96-tiles: 8 tiles per sel, so uniform
    if (sel == 2) {
        for (int ct = 0; ct < 3; ct++) {
            int col = n0 - 2 * DM + wc + ct * 16 + ln;
            int hh = col >> 6, dd = col & 63;
            float bv = bV[col];
            for (int rt = 0; rt < 4; rt++) {
                int row = m0 + wr + rt * 16 + qd * 4;
                int bb = row >> 11, ss = row & 2047;
                u16x4 pk;
                for (int r = 0; r < 4; r++) pk[r] = f2b(acc[rt][ct][r] + bv);
                *(u16x4*)&Vb[(((size_t)bb * NH + hh) * DH + dd) * SLEN + ss] = pk;
            }
        }
    } else {
        const float* bias = sel == 0 ? bQ : bK;
        u16* Out = sel == 0 ? Qb : Kb;
        const float qs = sel == 0 ? 0.125f * 1.44269504f : 1.0f;
        for (int ct = 0; ct < 3; ct++) {
            int col = n0 - sel * DM + wc + ct * 16 + ln;
            int hh = col >> 6, dd = col & 63;
            float bv = bias[col];
            for (int rt = 0; rt < 4; rt++) {
                int row = m0 + wr + rt * 16 + qd * 4;
                for (int r = 0; r < 4; r++) {
                    int rg = row + r;
                    int bb = rg >> 11, ss = rg & 2047;
                    Out[(((size_t)bb * NH + hh) * SLEN + ss) * DH + dd] = f2b((acc[rt][ct][r] + bv) * qs);
                }
            }
        }
    }
}

// ---------------- split-K flash attention, transposed-S, no-max softmax ----------------

__device__ __forceinline__ void cid2qc(int cid, int& qt, int& c, int& nc) {
    if (cid < 8)       { qt = cid;                 c = 0;              nc = 1; }
    else if (cid < 24) { qt = 8 + ((cid - 8) >> 1); c = (cid - 8) & 1; nc = 2; }
    else if (cid < 48) { qt = 16 + (cid - 24) / 3;  c = (cid - 24) % 3; nc = 3; }
    else               { qt = 24 + ((cid - 48) >> 2); c = (cid - 48) & 3; nc = 4; }
}

__global__ __launch_bounds__(256, 4) void attn(const u16* __restrict__ Qb, const u16* __restrict__ Kb,
                                               const u16* __restrict__ Vtg,
                                               u16* __restrict__ Po, float* __restrict__ Plv) {
    __shared__ u16 Kl[64 * 72];
    __shared__ u16 Vt[64 * 72];          // [d][k]
    __shared__ u16 Pq[4][16 * 72];       // wave-private P: [q-local][k]
    int cid = blockIdx.x, bh = blockIdx.y;
    int qt, c, nc;
    cid2qc(cid, qt, c, nc);
    int ntiles = qt + 1;
    int kt0 = c * ntiles / nc, kt1 = (c + 1) * ntiles / nc;
    const u16* Qp = Qb + (size_t)bh * SLEN * DH;
    const u16* Kp = Kb + (size_t)bh * SLEN * DH;
    const u16* Vp = Vtg + (size_t)bh * SLEN * DH;  // [d][s]
    int t = threadIdx.x, lane = t & 63, w = t >> 6;
    int ln = lane & 15, qd = lane >> 4;
    int qw = qt * 64 + w * 16;

    bf16x8 qf[2];
    for (int ks = 0; ks < 2; ks++)
        qf[ks] = *(const bf16x8*)(Qp + (size_t)(qw + ln) * DH + ks * 32 + qd * 8);

    float l = 0.f;
    f32x4 o[4] = {};

    u16x8 kr[2], vr[2];
    int sr = t >> 3, scf = t & 7;
    auto preload = [&](int kt) {
        int k0 = kt * 64;
        for (int j = 0; j < 2; j++) {
            int r = sr + 32 * j;
            kr[j] = *(const u16x8*)(Kp + (size_t)(k0 + r) * DH + scf * 8);
            vr[j] = *(const u16x8*)(Vp + (size_t)r * SLEN + k0 + scf * 8);
        }
    };
    preload(kt0);

    u16* Pw = Pq[w];
    for (int kt = kt0; kt < kt1; kt++) {
        __syncthreads();
        for (int j = 0; j < 2; j++) {
            int r = sr + 32 * j;
            *(u16x8*)&Kl[r * 72 + scf * 8] = kr[j];
            *(u16x8*)&Vt[r * 72 + scf * 8] = vr[j];
        }
        __syncthreads();
        if (kt + 1 < kt1) preload(kt + 1);

        f32x4 sf[4] = {};
        for (int ks = 0; ks < 2; ks++)
            for (int ct = 0; ct < 4; ct++) {
                bf16x8 kf = *(const bf16x8*)&Kl[(ct * 16 + ln) * 72 + ks * 32 + qd * 8];
                sf[ct] = __builtin_amdgcn_mfma_f32_16x16x32_bf16(kf, qf[ks], sf[ct], 0, 0, 0);
            }

        if (kt == qt) {
            int qg = qw + ln;
            for (int ct = 0; ct < 4; ct++)
                for (int r = 0; r < 4; r++) {
                    int kg = kt * 64 + ct * 16 + qd * 4 + r;
                    if (kg > qg) sf[ct][r] = -1e30f;
                }
        }

        float s = 0.f;
        for (int ct = 0; ct < 4; ct++) {
            u32 eb[4];
            for (int r = 0; r < 4; r++) {
                float e = exp2f(sf[ct][r]);
                u32 ub = __builtin_bit_cast(u32, e) & 0xFFFF0000u;
                eb[r] = __builtin_bit_cast(u32, e);
                s += __builtin_bit_cast(float, ub);
            }
            u32 p01 = __builtin_amdgcn_perm(eb[1], eb[0], 0x07060302u);
            u32 p23 = __builtin_amdgcn_perm(eb[3], eb[2], 0x07060302u);
            uint2 pk; pk.x = p01; pk.y = p23;
            *(uint2*)&Pw[ln * 72 + ct * 16 + qd * 4] = pk;
        }
        l += s;

        for (int ks = 0; ks < 2; ks++) {
            bf16x8 pf = *(const bf16x8*)&Pw[ln * 72 + ks * 32 + qd * 8];
            for (int dt = 0; dt < 4; dt++) {
                bf16x8 vf = *(const bf16x8*)&Vt[(dt * 16 + ln) * 72 + ks * 32 + qd * 8];
                o[dt] = __builtin_amdgcn_mfma_f32_16x16x32_bf16(vf, pf, o[dt], 0, 0, 0);
            }
        }
    }

    l += __shfl_xor(l, 16, 64);
    l += __shfl_xor(l, 32, 64);

    size_t pid = (size_t)bh * NCHUNK + cid;
    u16* op = Po + pid * 4096;
    for (int dt = 0; dt < 4; dt++) {
        u16x4 ov;
        ov[0] = f2b(o[dt][0]); ov[1] = f2b(o[dt][1]);
        ov[2] = f2b(o[dt][2]); ov[3] = f2b(o[dt][3]);
        *(u16x4*)&op[(w * 16 + ln) * 64 + dt * 16 + qd * 4] = ov;
    }
    if (qd == 0)
        Plv[pid * 64 + w * 16 + ln] = l;
}

// ---------------- combine partials -> Z bf16 [4096][768] ----------------

__global__ __launch_bounds__(256) void combine(const u16* __restrict__ Po, const float* __restrict__ Plv,
                                               u16* __restrict__ Zb) {
    int qt = blockIdx.x, bh = blockIdx.y;
    int b = bh / NH, h = bh % NH;
    int nc = (qt >> 3) + 1;
    int base;
    if (qt < 8) base = qt;
    else if (qt < 16) base = 8 + (qt - 8) * 2;
    else if (qt < 24) base = 24 + (qt - 16) * 3;
    else base = 48 + (qt - 24) * 4;
    int t = threadIdx.x;
    int q = t >> 2, dseg = (t & 3) * 16;

    float acc[16] = {};
    float lsum = 0.f;
    for (int cc = 0; cc < nc; cc++) {
        size_t pid = (size_t)bh * NCHUNK + base + cc;
        lsum += Plv[pid * 64 + q];
        const u16* op = Po + pid * 4096 + q * 64 + dseg;
        for (int j = 0; j < 2; j++) {
            u16x8 v = *(const u16x8*)(op + j * 8);
            for (int e = 0; e < 8; e++)
                acc[j * 8 + e] += b2f(v[e]);
        }
    }
    float inv = 1.0f / lsum;
    u16* Zp = Zb + ((size_t)b * SLEN + qt * 64 + q) * DM + h * DH + dseg;
    u16x8 ov;
    for (int j = 0; j < 2; j++) {
        for (int e = 0; e < 8; e++) ov[e] = f2b(acc[j * 8 + e] * inv);
        *(u16x8*)(Zp + j * 8) = ov;
    }
}

// ---------------- output projection (128x64 tile, register-preload pipeline) ----------------

__global__ __launch_bounds__(256) void gemm_proj(const u16* __restrict__ A, const u16* __restrict__ Bt,
                                                 const float* __restrict__ bO, float* __restrict__ out) {
    __shared__ u16 Al[128 * 72];
    __shared__ u16 Bl[64 * 72];
    int t = threadIdx.x;
    int n0 = blockIdx.x * 64, m0 = blockIdx.y * 128;
    int lane = t & 63, w = t >> 6;
    int ln = lane & 15, qd = lane >> 4;
    int wr = (w & 1) * 64, wc = (w >> 1) * 32;
    int sr = t >> 3, scf = t & 7;
    f32x4 acc[4][2] = {};

    float4 ar[4], br[2];
    auto preload = [&](int kt) {
        const u16* Ap = A + (size_t)m0 * DM + kt * 64;
        const u16* Bp = Bt + (size_t)n0 * DM + kt * 64;
        for (int j = 0; j < 4; j++)
            ar[j] = *(const float4*)(Ap + (size_t)(sr + 32 * j) * DM + scf * 8);
        for (int j = 0; j < 2; j++)
            br[j] = *(const float4*)(Bp + (size_t)(sr + 32 * j) * DM + scf * 8);
    };
    preload(0);

    for (int kt = 0; kt < DM / 64; kt++) {
        __syncthreads();
        for (int j = 0; j < 4; j++)
            *(float4*)&Al[(sr + 32 * j) * 72 + scf * 8] = ar[j];
        for (int j = 0; j < 2; j++)
            *(float4*)&Bl[(sr + 32 * j) * 72 + scf * 8] = br[j];
        __syncthreads();
        if (kt + 1 < DM / 64) preload(kt + 1);
        for (int ks = 0; ks < 2; ks++) {
            bf16x8 af[4], bfr[2];
            for (int rt = 0; rt < 4; rt++)
                af[rt] = *(const bf16x8*)&Al[(wr + rt * 16 + ln) * 72 + ks * 32 + qd * 8];
            for (int ct = 0; ct < 2; ct++)
                bfr[ct] = *(const bf16x8*)&Bl[(wc + ct * 16 + ln) * 72 + ks * 32 + qd * 8];
            for (int rt = 0; rt < 4; rt++)
                for (int ct = 0; ct < 2; ct++)
                    acc[rt][ct] = __builtin_amdgcn_mfma_f32_16x16x32_bf16(af[rt], bfr[ct], acc[rt][ct], 0, 0, 0);
        }
    }
    for (int ct = 0; ct < 2; ct++) {
        int col = n0 + wc + ct * 16 + ln;
        float bv = bO[col];
        for (int rt = 0; rt < 4; rt++) {
            int row = m0 + wr + rt * 16 + qd * 4;
            for (int r = 0; r < 4; r++)
                out[(size_t)(row + r) * DM + col] = acc[rt][ct][r] + bv;
        }
    }
}

// ---------------- launch ----------------

extern "C" void kernel_launch(void* const* d_in, const int* in_sizes, int n_in,
                              void* d_out, int out_size, void* d_ws, size_t ws_size,
                              hipStream_t stream) {
    const float* x  = (const float*)d_in[0];
    const float* WQ = (const float*)d_in[1];
    const float* bQ = (const float*)d_in[2];
    const float* WK = (const float*)d_in[3];
    const float* bK = (const float*)d_in[4];
    const float* WV = (const float*)d_in[5];
    const float* bV = (const float*)d_in[6];
    const float* WO = (const float*)d_in[7];
    const float* bO = (const float*)d_in[8];
    float* out = (float*)d_out;

    u16* xb   = (u16*)d_ws;                        // [4096][768]
    u16* wqkv = xb + (size_t)ROWS * DM;            // [2304][768]
    u16* wo   = wqkv + (size_t)NQKV * DM;          // [768][768]
    u16* Qb   = wo + (size_t)DM * DM;
    size_t hsz = (size_t)BATCH * NH * SLEN * DH;
    u16* Kb   = Qb + hsz;
    u16* Vb   = Kb + hsz;                          // V^T [b,h,d,s]
    u16* Zb   = Vb + hsz;                          // [4096][768]
    u16* Po   = Zb + (size_t)ROWS * DM;            // partials o: [24*80][64][64] bf16
    float* Pl = (float*)(Po + (size_t)BATCH * NH * NCHUNK * 4096);

    pack_x<<<ROWS * DM / 2048, 256, 0, stream>>>(x, xb);
    pack_wqkv<<<dim3(12, 12, 3), 256, 0, stream>>>(WQ, WK, WV, wqkv);
    pack_wo<<<dim3(12, 12), 256, 0, stream>>>(WO, wo);
    gemm_qkv<<<dim3(NQKV / 96, ROWS / 128), 256, 0, stream>>>(xb, wqkv, bQ, bK, bV, Qb, Kb, Vb);
    attn<<<dim3(NCHUNK, BATCH * NH), 256, 0, stream>>>(Qb, Kb, Vb, Po, Pl);
    combine<<<dim3(SLEN / 64, BATCH * NH), 256, 0, stream>>>(Po, Pl, Zb);
    gemm_proj<<<dim3(DM / 64, ROWS / 128), 256, 0, stream>>>(Zb, wo, bO, out);
}

// Round 6
// 237.387 us; speedup vs baseline: 1.0548x; 1.0548x over previous
//
#include <hip/hip_runtime.h>
#include <hip/hip_bf16.h>

#define BATCH 2
#define SLEN 2048
#define NH 12
#define DM 768
#define DH 64
#define ROWS (BATCH*SLEN)   // 4096
#define NQKV (3*DM)         // 2304
#define NCHUNK 80           // split-K chunks per bh (chunk = up to 8 k-tiles)

typedef __attribute__((ext_vector_type(8))) short bf16x8;
typedef __attribute__((ext_vector_type(4))) float f32x4;
typedef unsigned short u16;
typedef unsigned int u32;
typedef __attribute__((ext_vector_type(4))) unsigned short u16x4;
typedef __attribute__((ext_vector_type(8))) unsigned short u16x8;

__device__ __forceinline__ u16 f2b(float f) {
    unsigned int u = __builtin_bit_cast(unsigned int, f);
    unsigned int r = (u + 0x7FFFu + ((u >> 16) & 1u)) >> 16;
    return (u16)r;
}
__device__ __forceinline__ float b2f(u16 v) {
    unsigned int u = ((unsigned int)v) << 16;
    return __builtin_bit_cast(float, u);
}

// ---------------- pack kernels ----------------

__global__ __launch_bounds__(256) void pack_x(const float* __restrict__ x, u16* __restrict__ xb) {
    int i = blockIdx.x * 256 + threadIdx.x;
    const float4* xv = (const float4*)x;
    float4 a = xv[i * 2], b = xv[i * 2 + 1];
    u16x8 o;
    o[0] = f2b(a.x); o[1] = f2b(a.y); o[2] = f2b(a.z); o[3] = f2b(a.w);
    o[4] = f2b(b.x); o[5] = f2b(b.y); o[6] = f2b(b.z); o[7] = f2b(b.w);
    *(u16x8*)(xb + (size_t)i * 8) = o;
}

__global__ __launch_bounds__(256) void pack_wqkv(const float* __restrict__ WQ, const float* __restrict__ WK,
                                                 const float* __restrict__ WV, u16* __restrict__ out) {
    __shared__ u16 L[64 * 72];
    int mt = blockIdx.x, h = blockIdx.y, sel = blockIdx.z;
    const float* W = sel == 0 ? WQ : (sel == 1 ? WK : WV);
    const float* src = W + ((size_t)h * DM + mt * 64) * DH;
    int t = threadIdx.x;
    for (int j = 0; j < 4; j++) {
        int i = t + 256 * j;
        int r = i >> 4, cf = i & 15;
        float4 v = ((const float4*)src)[i];
        u16x4 o; o[0] = f2b(v.x); o[1] = f2b(v.y); o[2] = f2b(v.z); o[3] = f2b(v.w);
        *(u16x4*)&L[r * 72 + cf * 4] = o;
    }
    __syncthreads();
    u16* orow = out + ((size_t)(sel * DM + h * DH)) * DM + mt * 64;
    for (int j = 0; j < 16; j++) {
        int e = t + 256 * j;
        int d = e >> 6, mm = e & 63;
        orow[(size_t)d * DM + mm] = L[mm * 72 + d];
    }
}

__global__ __launch_bounds__(256) void pack_wo(const float* __restrict__ WO, u16* __restrict__ out) {
    __shared__ u16 L[64 * 72];
    int bi = blockIdx.x, bj = blockIdx.y;
    int t = threadIdx.x;
    for (int j = 0; j < 4; j++) {
        int i = t + 256 * j;
        int r = i >> 4, cf = i & 15;
        float4 v = ((const float4*)(WO + (size_t)(bi * 64 + r) * DM + bj * 64))[cf];
        u16x4 o; o[0] = f2b(v.x); o[1] = f2b(v.y); o[2] = f2b(v.z); o[3] = f2b(v.w);
        *(u16x4*)&L[r * 72 + cf * 4] = o;
    }
    __syncthreads();
    for (int j = 0; j < 16; j++) {
        int e = t + 256 * j;
        int c = e >> 6, r = e & 63;
        out[(size_t)(bj * 64 + c) * DM + bi * 64 + r] = L[r * 72 + c];
    }
}

// ---------------- QKV GEMM (128x128 tile, register-preload pipeline) ----------------
// -> Q(pre-scaled by 0.125*log2e)/K [b,h,s,d], V^T [b,h,d,s]
// Identical to the round-4 kernel EXCEPT the k-loop staging loads are hoisted
// into registers one iteration ahead (single-variable A/B vs round 4).

__global__ __launch_bounds__(256) void gemm_qkv(const u16* __restrict__ A, const u16* __restrict__ Bt,
                                                const float* __restrict__ bQ, const float* __restrict__ bK,
                                                const float* __restrict__ bV,
                                                u16* __restrict__ Qb, u16* __restrict__ Kb, u16* __restrict__ Vb) {
    __shared__ u16 Al[128 * 72];
    __shared__ u16 Bl[128 * 72];
    int t = threadIdx.x;
    int n0 = blockIdx.x * 128, m0 = blockIdx.y * 128;
    int lane = t & 63, w = t >> 6;
    int ln = lane & 15, qd = lane >> 4;
    int wr = (w & 1) * 64, wc = (w >> 1) * 64;
    int sr = t >> 3, scf = t & 7;        // staging coords: 32 rows x 8 col-chunks
    f32x4 acc[4][4] = {};

    float4 ar[4], br[4];
    auto preload = [&](int kt) {
        const u16* Ap = A + (size_t)m0 * DM + kt * 64;
        const u16* Bp = Bt + (size_t)n0 * DM + kt * 64;
        for (int j = 0; j < 4; j++)
            ar[j] = *(const float4*)(Ap + (size_t)(sr + 32 * j) * DM + scf * 8);
        for (int j = 0; j < 4; j++)
            br[j] = *(const float4*)(Bp + (size_t)(sr + 32 * j) * DM + scf * 8);
    };
    preload(0);

    for (int kt = 0; kt < DM / 64; kt++) {
        __syncthreads();
        for (int j = 0; j < 4; j++)
            *(float4*)&Al[(sr + 32 * j) * 72 + scf * 8] = ar[j];
        for (int j = 0; j < 4; j++)
            *(float4*)&Bl[(sr + 32 * j) * 72 + scf * 8] = br[j];
        __syncthreads();
        if (kt + 1 < DM / 64) preload(kt + 1);
        for (int ks = 0; ks < 2; ks++) {
            bf16x8 af[4], bfr[4];
            for (int rt = 0; rt < 4; rt++)
                af[rt] = *(const bf16x8*)&Al[(wr + rt * 16 + ln) * 72 + ks * 32 + qd * 8];
            for (int ct = 0; ct < 4; ct++)
                bfr[ct] = *(const bf16x8*)&Bl[(wc + ct * 16 + ln) * 72 + ks * 32 + qd * 8];
            for (int rt = 0; rt < 4; rt++)
                for (int ct = 0; ct < 4; ct++)
                    acc[rt][ct] = __builtin_amdgcn_mfma_f32_16x16x32_bf16(af[rt], bfr[ct], acc[rt][ct], 0, 0, 0);
        }
    }
    int sel = n0 / DM;
    if (sel == 2) {
        // V^T: [b,h,d,s] with packed 4-wide stores along s
        for (int ct = 0; ct < 4; ct++) {
            int col = n0 - 2 * DM + wc + ct * 16 + ln;
            int hh = col >> 6, dd = col & 63;
            float bv = bV[col];
            for (int rt = 0; rt < 4; rt++) {
                int row = m0 + wr + rt * 16 + qd * 4;
                int bb = row >> 11, ss = row & 2047;
                u16x4 pk;
                for (int r = 0; r < 4; r++) pk[r] = f2b(acc[rt][ct][r] + bv);
                *(u16x4*)&Vb[(((size_t)bb * NH + hh) * DH + dd) * SLEN + ss] = pk;
            }
        }
    } else {
        const float* bias = sel == 0 ? bQ : bK;
        u16* Out = sel == 0 ? Qb : Kb;
        const float qs = sel == 0 ? 0.125f * 1.44269504f : 1.0f;
        for (int ct = 0; ct < 4; ct++) {
            int col = n0 - sel * DM + wc + ct * 16 + ln;
            int hh = col >> 6, dd = col & 63;
            float bv = bias[col];
            for (int rt = 0; rt < 4; rt++) {
                int row = m0 + wr + rt * 16 + qd * 4;
                for (int r = 0; r < 4; r++) {
                    int rg = row + r;
                    int bb = rg >> 11, ss = rg & 2047;
                    Out[(((size_t)bb * NH + hh) * SLEN + ss) * DH + dd] = f2b((acc[rt][ct][r] + bv) * qs);
                }
            }
        }
    }
}

// ---------------- split-K flash attention, transposed-S, no-max softmax ----------------

__device__ __forceinline__ void cid2qc(int cid, int& qt, int& c, int& nc) {
    if (cid < 8)       { qt = cid;                 c = 0;              nc = 1; }
    else if (cid < 24) { qt = 8 + ((cid - 8) >> 1); c = (cid - 8) & 1; nc = 2; }
    else if (cid < 48) { qt = 16 + (cid - 24) / 3;  c = (cid - 24) % 3; nc = 3; }
    else               { qt = 24 + ((cid - 48) >> 2); c = (cid - 48) & 3; nc = 4; }
}

__global__ __launch_bounds__(256, 4) void attn(const u16* __restrict__ Qb, const u16* __restrict__ Kb,
                                               const u16* __restrict__ Vtg,
                                               u16* __restrict__ Po, float* __restrict__ Plv) {
    __shared__ u16 Kl[64 * 72];
    __shared__ u16 Vt[64 * 72];          // [d][k]
    __shared__ u16 Pq[4][16 * 72];       // wave-private P: [q-local][k]
    int cid = blockIdx.x, bh = blockIdx.y;
    int qt, c, nc;
    cid2qc(cid, qt, c, nc);
    int ntiles = qt + 1;
    int kt0 = c * ntiles / nc, kt1 = (c + 1) * ntiles / nc;
    const u16* Qp = Qb + (size_t)bh * SLEN * DH;
    const u16* Kp = Kb + (size_t)bh * SLEN * DH;
    const u16* Vp = Vtg + (size_t)bh * SLEN * DH;  // [d][s]
    int t = threadIdx.x, lane = t & 63, w = t >> 6;
    int ln = lane & 15, qd = lane >> 4;
    int qw = qt * 64 + w * 16;

    bf16x8 qf[2];
    for (int ks = 0; ks < 2; ks++)
        qf[ks] = *(const bf16x8*)(Qp + (size_t)(qw + ln) * DH + ks * 32 + qd * 8);

    float l = 0.f;
    f32x4 o[4] = {};

    u16x8 kr[2], vr[2];
    int sr = t >> 3, scf = t & 7;
    auto preload = [&](int kt) {
        int k0 = kt * 64;
        for (int j = 0; j < 2; j++) {
            int r = sr + 32 * j;
            kr[j] = *(const u16x8*)(Kp + (size_t)(k0 + r) * DH + scf * 8);
            vr[j] = *(const u16x8*)(Vp + (size_t)r * SLEN + k0 + scf * 8);
        }
    };
    preload(kt0);

    u16* Pw = Pq[w];
    for (int kt = kt0; kt < kt1; kt++) {
        __syncthreads();
        for (int j = 0; j < 2; j++) {
            int r = sr + 32 * j;
            *(u16x8*)&Kl[r * 72 + scf * 8] = kr[j];
            *(u16x8*)&Vt[r * 72 + scf * 8] = vr[j];
        }
        __syncthreads();
        if (kt + 1 < kt1) preload(kt + 1);

        f32x4 sf[4] = {};
        for (int ks = 0; ks < 2; ks++)
            for (int ct = 0; ct < 4; ct++) {
                bf16x8 kf = *(const bf16x8*)&Kl[(ct * 16 + ln) * 72 + ks * 32 + qd * 8];
                sf[ct] = __builtin_amdgcn_mfma_f32_16x16x32_bf16(kf, qf[ks], sf[ct], 0, 0, 0);
            }

        if (kt == qt) {
            int qg = qw + ln;
            for (int ct = 0; ct < 4; ct++)
                for (int r = 0; r < 4; r++) {
                    int kg = kt * 64 + ct * 16 + qd * 4 + r;
                    if (kg > qg) sf[ct][r] = -1e30f;
                }
        }

        float s = 0.f;
        for (int ct = 0; ct < 4; ct++) {
            u32 eb[4];
            for (int r = 0; r < 4; r++) {
                float e = exp2f(sf[ct][r]);
                u32 ub = __builtin_bit_cast(u32, e) & 0xFFFF0000u;
                eb[r] = __builtin_bit_cast(u32, e);
                s += __builtin_bit_cast(float, ub);
            }
            u32 p01 = __builtin_amdgcn_perm(eb[1], eb[0], 0x07060302u);
            u32 p23 = __builtin_amdgcn_perm(eb[3], eb[2], 0x07060302u);
            uint2 pk; pk.x = p01; pk.y = p23;
            *(uint2*)&Pw[ln * 72 + ct * 16 + qd * 4] = pk;
        }
        l += s;

        for (int ks = 0; ks < 2; ks++) {
            bf16x8 pf = *(const bf16x8*)&Pw[ln * 72 + ks * 32 + qd * 8];
            for (int dt = 0; dt < 4; dt++) {
                bf16x8 vf = *(const bf16x8*)&Vt[(dt * 16 + ln) * 72 + ks * 32 + qd * 8];
                o[dt] = __builtin_amdgcn_mfma_f32_16x16x32_bf16(vf, pf, o[dt], 0, 0, 0);
            }
        }
    }

    l += __shfl_xor(l, 16, 64);
    l += __shfl_xor(l, 32, 64);

    size_t pid = (size_t)bh * NCHUNK + cid;
    u16* op = Po + pid * 4096;
    for (int dt = 0; dt < 4; dt++) {
        u16x4 ov;
        ov[0] = f2b(o[dt][0]); ov[1] = f2b(o[dt][1]);
        ov[2] = f2b(o[dt][2]); ov[3] = f2b(o[dt][3]);
        *(u16x4*)&op[(w * 16 + ln) * 64 + dt * 16 + qd * 4] = ov;
    }
    if (qd == 0)
        Plv[pid * 64 + w * 16 + ln] = l;
}

// ---------------- combine partials -> Z bf16 [4096][768] ----------------

__global__ __launch_bounds__(256) void combine(const u16* __restrict__ Po, const float* __restrict__ Plv,
                                               u16* __restrict__ Zb) {
    int qt = blockIdx.x, bh = blockIdx.y;
    int b = bh / NH, h = bh % NH;
    int nc = (qt >> 3) + 1;
    int base;
    if (qt < 8) base = qt;
    else if (qt < 16) base = 8 + (qt - 8) * 2;
    else if (qt < 24) base = 24 + (qt - 16) * 3;
    else base = 48 + (qt - 24) * 4;
    int t = threadIdx.x;
    int q = t >> 2, dseg = (t & 3) * 16;

    float acc[16] = {};
    float lsum = 0.f;
    for (int cc = 0; cc < nc; cc++) {
        size_t pid = (size_t)bh * NCHUNK + base + cc;
        lsum += Plv[pid * 64 + q];
        const u16* op = Po + pid * 4096 + q * 64 + dseg;
        for (int j = 0; j < 2; j++) {
            u16x8 v = *(const u16x8*)(op + j * 8);
            for (int e = 0; e < 8; e++)
                acc[j * 8 + e] += b2f(v[e]);
        }
    }
    float inv = 1.0f / lsum;
    u16* Zp = Zb + ((size_t)b * SLEN + qt * 64 + q) * DM + h * DH + dseg;
    u16x8 ov;
    for (int j = 0; j < 2; j++) {
        for (int e = 0; e < 8; e++) ov[e] = f2b(acc[j * 8 + e] * inv);
        *(u16x8*)(Zp + j * 8) = ov;
    }
}

// ---------------- output projection (round-4 form: 128x128 tile) ----------------

__global__ __launch_bounds__(256) void gemm_proj(const u16* __restrict__ A, const u16* __restrict__ Bt,
                                                 const float* __restrict__ bO, float* __restrict__ out) {
    __shared__ u16 Al[128 * 72];
    __shared__ u16 Bl[128 * 72];
    int t = threadIdx.x;
    int n0 = blockIdx.x * 128, m0 = blockIdx.y * 128;
    int lane = t & 63, w = t >> 6;
    int ln = lane & 15, qd = lane >> 4;
    int wr = (w & 1) * 64, wc = (w >> 1) * 64;
    f32x4 acc[4][4] = {};
    for (int kt = 0; kt < DM / 64; kt++) {
        __syncthreads();
        for (int j = 0; j < 4; j++) {
            int i = t + 256 * j;
            int r = i >> 3, cf = i & 7;
            float4 va = *(const float4*)(A + (size_t)(m0 + r) * DM + kt * 64 + cf * 8);
            *(float4*)&Al[r * 72 + cf * 8] = va;
            float4 vb = *(const float4*)(Bt + (size_t)(n0 + r) * DM + kt * 64 + cf * 8);
            *(float4*)&Bl[r * 72 + cf * 8] = vb;
        }
        __syncthreads();
        for (int ks = 0; ks < 2; ks++) {
            bf16x8 af[4], bfr[4];
            for (int rt = 0; rt < 4; rt++)
                af[rt] = *(const bf16x8*)&Al[(wr + rt * 16 + ln) * 72 + ks * 32 + qd * 8];
            for (int ct = 0; ct < 4; ct++)
                bfr[ct] = *(const bf16x8*)&Bl[(wc + ct * 16 + ln) * 72 + ks * 32 + qd * 8];
            for (int rt = 0; rt < 4; rt++)
                for (int ct = 0; ct < 4; ct++)
                    acc[rt][ct] = __builtin_amdgcn_mfma_f32_16x16x32_bf16(af[rt], bfr[ct], acc[rt][ct], 0, 0, 0);
        }
    }
    for (int ct = 0; ct < 4; ct++) {
        int col = n0 + wc + ct * 16 + ln;
        float bv = bO[col];
        for (int rt = 0; rt < 4; rt++) {
            int row = m0 + wr + rt * 16 + qd * 4;
            for (int r = 0; r < 4; r++)
                out[(size_t)(row + r) * DM + col] = acc[rt][ct][r] + bv;
        }
    }
}

// ---------------- launch ----------------

extern "C" void kernel_launch(void* const* d_in, const int* in_sizes, int n_in,
                              void* d_out, int out_size, void* d_ws, size_t ws_size,
                              hipStream_t stream) {
    const float* x  = (const float*)d_in[0];
    const float* WQ = (const float*)d_in[1];
    const float* bQ = (const float*)d_in[2];
    const float* WK = (const float*)d_in[3];
    const float* bK = (const float*)d_in[4];
    const float* WV = (const float*)d_in[5];
    const float* bV = (const float*)d_in[6];
    const float* WO = (const float*)d_in[7];
    const float* bO = (const float*)d_in[8];
    float* out = (float*)d_out;

    u16* xb   = (u16*)d_ws;                        // [4096][768]
    u16* wqkv = xb + (size_t)ROWS * DM;            // [2304][768]
    u16* wo   = wqkv + (size_t)NQKV * DM;          // [768][768]
    u16* Qb   = wo + (size_t)DM * DM;
    size_t hsz = (size_t)BATCH * NH * SLEN * DH;
    u16* Kb   = Qb + hsz;
    u16* Vb   = Kb + hsz;                          // V^T [b,h,d,s]
    u16* Zb   = Vb + hsz;                          // [4096][768]
    u16* Po   = Zb + (size_t)ROWS * DM;            // partials o: [24*80][64][64] bf16
    float* Pl = (float*)(Po + (size_t)BATCH * NH * NCHUNK * 4096);

    pack_x<<<ROWS * DM / 2048, 256, 0, stream>>>(x, xb);
    pack_wqkv<<<dim3(12, 12, 3), 256, 0, stream>>>(WQ, WK, WV, wqkv);
    pack_wo<<<dim3(12, 12), 256, 0, stream>>>(WO, wo);
    gemm_qkv<<<dim3(NQKV / 128, ROWS / 128), 256, 0, stream>>>(xb, wqkv, bQ, bK, bV, Qb, Kb, Vb);
    attn<<<dim3(NCHUNK, BATCH * NH), 256, 0, stream>>>(Qb, Kb, Vb, Po, Pl);
    combine<<<dim3(SLEN / 64, BATCH * NH), 256, 0, stream>>>(Po, Pl, Zb);
    gemm_proj<<<dim3(DM / 128, ROWS / 128), 256, 0, stream>>>(Zb, wo, bO, out);
}

// Round 7
// 173.462 us; speedup vs baseline: 1.4435x; 1.3685x over previous
//
#include <hip/hip_runtime.h>
#include <hip/hip_bf16.h>

#define BATCH 2
#define SLEN 2048
#define NH 12
#define DM 768
#define DH 64
#define ROWS (BATCH*SLEN)   // 4096
#define NQKV (3*DM)         // 2304
#define NCHUNK 80           // split-K chunks per bh (chunk = up to 8 k-tiles)

typedef __attribute__((ext_vector_type(8))) short bf16x8;
typedef __attribute__((ext_vector_type(4))) float f32x4;
typedef unsigned short u16;
typedef unsigned int u32;
typedef __attribute__((ext_vector_type(4))) unsigned short u16x4;
typedef __attribute__((ext_vector_type(8))) unsigned short u16x8;

__device__ __forceinline__ u16 f2b(float f) {
    unsigned int u = __builtin_bit_cast(unsigned int, f);
    unsigned int r = (u + 0x7FFFu + ((u >> 16) & 1u)) >> 16;
    return (u16)r;
}
__device__ __forceinline__ float b2f(u16 v) {
    unsigned int u = ((unsigned int)v) << 16;
    return __builtin_bit_cast(float, u);
}

// async global->LDS, 16B per lane. LDS dest = wave-uniform base + lane*16.
__device__ __forceinline__ void gload16(const u16* g, u16* l) {
    __builtin_amdgcn_global_load_lds(
        (const __attribute__((address_space(1))) unsigned int*)g,
        (__attribute__((address_space(3))) unsigned int*)l,
        16, 0, 0);
}

// ---------------- pack kernels ----------------

__global__ __launch_bounds__(256) void pack_x(const float* __restrict__ x, u16* __restrict__ xb) {
    int i = blockIdx.x * 256 + threadIdx.x;
    const float4* xv = (const float4*)x;
    float4 a = xv[i * 2], b = xv[i * 2 + 1];
    u16x8 o;
    o[0] = f2b(a.x); o[1] = f2b(a.y); o[2] = f2b(a.z); o[3] = f2b(a.w);
    o[4] = f2b(b.x); o[5] = f2b(b.y); o[6] = f2b(b.z); o[7] = f2b(b.w);
    *(u16x8*)(xb + (size_t)i * 8) = o;
}

__global__ __launch_bounds__(256) void pack_wqkv(const float* __restrict__ WQ, const float* __restrict__ WK,
                                                 const float* __restrict__ WV, u16* __restrict__ out) {
    __shared__ u16 L[64 * 72];
    int mt = blockIdx.x, h = blockIdx.y, sel = blockIdx.z;
    const float* W = sel == 0 ? WQ : (sel == 1 ? WK : WV);
    const float* src = W + ((size_t)h * DM + mt * 64) * DH;
    int t = threadIdx.x;
    for (int j = 0; j < 4; j++) {
        int i = t + 256 * j;
        int r = i >> 4, cf = i & 15;
        float4 v = ((const float4*)src)[i];
        u16x4 o; o[0] = f2b(v.x); o[1] = f2b(v.y); o[2] = f2b(v.z); o[3] = f2b(v.w);
        *(u16x4*)&L[r * 72 + cf * 4] = o;
    }
    __syncthreads();
    u16* orow = out + ((size_t)(sel * DM + h * DH)) * DM + mt * 64;
    for (int j = 0; j < 16; j++) {
        int e = t + 256 * j;
        int d = e >> 6, mm = e & 63;
        orow[(size_t)d * DM + mm] = L[mm * 72 + d];
    }
}

__global__ __launch_bounds__(256) void pack_wo(const float* __restrict__ WO, u16* __restrict__ out) {
    __shared__ u16 L[64 * 72];
    int bi = blockIdx.x, bj = blockIdx.y;
    int t = threadIdx.x;
    for (int j = 0; j < 4; j++) {
        int i = t + 256 * j;
        int r = i >> 4, cf = i & 15;
        float4 v = ((const float4*)(WO + (size_t)(bi * 64 + r) * DM + bj * 64))[cf];
        u16x4 o; o[0] = f2b(v.x); o[1] = f2b(v.y); o[2] = f2b(v.z); o[3] = f2b(v.w);
        *(u16x4*)&L[r * 72 + cf * 4] = o;
    }
    __syncthreads();
    for (int j = 0; j < 16; j++) {
        int e = t + 256 * j;
        int c = e >> 6, r = e & 63;
        out[(size_t)(bj * 64 + c) * DM + bi * 64 + r] = L[r * 72 + c];
    }
}

// ---------------- QKV GEMM (128x128, global_load_lds staging, XOR-swizzled LDS) ----
// LDS layout: [row][64 u16], 16B chunk c of row r stored at slot c^(r&7).
// -> Q(pre-scaled by 0.125*log2e)/K [b,h,s,d], V^T [b,h,d,s]

__global__ __launch_bounds__(256) void gemm_qkv(const u16* __restrict__ A, const u16* __restrict__ Bt,
                                                const float* __restrict__ bQ, const float* __restrict__ bK,
                                                const float* __restrict__ bV,
                                                u16* __restrict__ Qb, u16* __restrict__ Kb, u16* __restrict__ Vb) {
    __shared__ u16 Al[128 * 64];
    __shared__ u16 Bl[128 * 64];
    int t = threadIdx.x;
    int n0 = blockIdx.x * 128, m0 = blockIdx.y * 128;
    int lane = t & 63, w = t >> 6;
    int ln = lane & 15, qd = lane >> 4;
    int wr = (w & 1) * 64, wc = (w >> 1) * 64;
    int srow = lane >> 3, slot = lane & 7;
    f32x4 acc[4][4] = {};

    for (int kt = 0; kt < DM / 64; kt++) {
        __syncthreads();
        for (int j = 0; j < 4; j++) {
            int r = w * 32 + j * 8 + srow;
            int gc = slot ^ (r & 7);
            gload16(A + (size_t)(m0 + r) * DM + kt * 64 + gc * 8, &Al[(w * 32 + j * 8) * 64]);
            gload16(Bt + (size_t)(n0 + r) * DM + kt * 64 + gc * 8, &Bl[(w * 32 + j * 8) * 64]);
        }
        __syncthreads();   // drains vmcnt -> tile visible
        for (int ks = 0; ks < 2; ks++) {
            int sl = ((ks * 4 + qd) ^ (ln & 7)) * 8;
            bf16x8 af[4], bfr[4];
            for (int rt = 0; rt < 4; rt++)
                af[rt] = *(const bf16x8*)&Al[(wr + rt * 16 + ln) * 64 + sl];
            for (int ct = 0; ct < 4; ct++)
                bfr[ct] = *(const bf16x8*)&Bl[(wc + ct * 16 + ln) * 64 + sl];
            for (int rt = 0; rt < 4; rt++)
                for (int ct = 0; ct < 4; ct++)
                    acc[rt][ct] = __builtin_amdgcn_mfma_f32_16x16x32_bf16(af[rt], bfr[ct], acc[rt][ct], 0, 0, 0);
        }
    }
    int sel = n0 / DM;
    if (sel == 2) {
        for (int ct = 0; ct < 4; ct++) {
            int col = n0 - 2 * DM + wc + ct * 16 + ln;
            int hh = col >> 6, dd = col & 63;
            float bv = bV[col];
            for (int rt = 0; rt < 4; rt++) {
                int row = m0 + wr + rt * 16 + qd * 4;
                int bb = row >> 11, ss = row & 2047;
                u16x4 pk;
                for (int r = 0; r < 4; r++) pk[r] = f2b(acc[rt][ct][r] + bv);
                *(u16x4*)&Vb[(((size_t)bb * NH + hh) * DH + dd) * SLEN + ss] = pk;
            }
        }
    } else {
        const float* bias = sel == 0 ? bQ : bK;
        u16* Out = sel == 0 ? Qb : Kb;
        const float qs = sel == 0 ? 0.125f * 1.44269504f : 1.0f;
        for (int ct = 0; ct < 4; ct++) {
            int col = n0 - sel * DM + wc + ct * 16 + ln;
            int hh = col >> 6, dd = col & 63;
            float bv = bias[col];
            for (int rt = 0; rt < 4; rt++) {
                int row = m0 + wr + rt * 16 + qd * 4;
                for (int r = 0; r < 4; r++) {
                    int rg = row + r;
                    int bb = rg >> 11, ss = rg & 2047;
                    Out[(((size_t)bb * NH + hh) * SLEN + ss) * DH + dd] = f2b((acc[rt][ct][r] + bv) * qs);
                }
            }
        }
    }
}

// ---------------- split-K flash attention, transposed-S, no-max softmax ----------------

__device__ __forceinline__ void cid2qc(int cid, int& qt, int& c, int& nc) {
    if (cid < 8)       { qt = cid;                 c = 0;              nc = 1; }
    else if (cid < 24) { qt = 8 + ((cid - 8) >> 1); c = (cid - 8) & 1; nc = 2; }
    else if (cid < 48) { qt = 16 + (cid - 24) / 3;  c = (cid - 24) % 3; nc = 3; }
    else               { qt = 24 + ((cid - 48) >> 2); c = (cid - 48) & 3; nc = 4; }
}

__global__ __launch_bounds__(256, 4) void attn(const u16* __restrict__ Qb, const u16* __restrict__ Kb,
                                               const u16* __restrict__ Vtg,
                                               u16* __restrict__ Po, float* __restrict__ Plv) {
    __shared__ u16 Kl[64 * 72];
    __shared__ u16 Vt[64 * 72];          // [d][k]
    __shared__ u16 Pq[4][16 * 72];       // wave-private P: [q-local][k]
    int cid = blockIdx.x, bh = blockIdx.y;
    int qt, c, nc;
    cid2qc(cid, qt, c, nc);
    int ntiles = qt + 1;
    int kt0 = c * ntiles / nc, kt1 = (c + 1) * ntiles / nc;
    const u16* Qp = Qb + (size_t)bh * SLEN * DH;
    const u16* Kp = Kb + (size_t)bh * SLEN * DH;
    const u16* Vp = Vtg + (size_t)bh * SLEN * DH;  // [d][s]
    int t = threadIdx.x, lane = t & 63, w = t >> 6;
    int ln = lane & 15, qd = lane >> 4;
    int qw = qt * 64 + w * 16;

    bf16x8 qf[2];
    for (int ks = 0; ks < 2; ks++)
        qf[ks] = *(const bf16x8*)(Qp + (size_t)(qw + ln) * DH + ks * 32 + qd * 8);

    float l = 0.f;
    f32x4 o[4] = {};

    u16x8 kr[2], vr[2];
    int sr = t >> 3, scf = t & 7;
    auto preload = [&](int kt) {
        int k0 = kt * 64;
        for (int j = 0; j < 2; j++) {
            int r = sr + 32 * j;
            kr[j] = *(const u16x8*)(Kp + (size_t)(k0 + r) * DH + scf * 8);
            vr[j] = *(const u16x8*)(Vp + (size_t)r * SLEN + k0 + scf * 8);
        }
    };
    preload(kt0);

    u16* Pw = Pq[w];
    for (int kt = kt0; kt < kt1; kt++) {
        __syncthreads();
        for (int j = 0; j < 2; j++) {
            int r = sr + 32 * j;
            *(u16x8*)&Kl[r * 72 + scf * 8] = kr[j];
            *(u16x8*)&Vt[r * 72 + scf * 8] = vr[j];
        }
        __syncthreads();
        if (kt + 1 < kt1) preload(kt + 1);

        f32x4 sf[4] = {};
        for (int ks = 0; ks < 2; ks++)
            for (int ct = 0; ct < 4; ct++) {
                bf16x8 kf = *(const bf16x8*)&Kl[(ct * 16 + ln) * 72 + ks * 32 + qd * 8];
                sf[ct] = __builtin_amdgcn_mfma_f32_16x16x32_bf16(kf, qf[ks], sf[ct], 0, 0, 0);
            }

        if (kt == qt) {
            int qg = qw + ln;
            for (int ct = 0; ct < 4; ct++)
                for (int r = 0; r < 4; r++) {
                    int kg = kt * 64 + ct * 16 + qd * 4 + r;
                    if (kg > qg) sf[ct][r] = -1e30f;
                }
        }

        float s = 0.f;
        for (int ct = 0; ct < 4; ct++) {
            u32 eb[4];
            for (int r = 0; r < 4; r++) {
                float e = exp2f(sf[ct][r]);
                u32 ub = __builtin_bit_cast(u32, e) & 0xFFFF0000u;
                eb[r] = __builtin_bit_cast(u32, e);
                s += __builtin_bit_cast(float, ub);
            }
            u32 p01 = __builtin_amdgcn_perm(eb[1], eb[0], 0x07060302u);
            u32 p23 = __builtin_amdgcn_perm(eb[3], eb[2], 0x07060302u);
            uint2 pk; pk.x = p01; pk.y = p23;
            *(uint2*)&Pw[ln * 72 + ct * 16 + qd * 4] = pk;
        }
        l += s;

        for (int ks = 0; ks < 2; ks++) {
            bf16x8 pf = *(const bf16x8*)&Pw[ln * 72 + ks * 32 + qd * 8];
            for (int dt = 0; dt < 4; dt++) {
                bf16x8 vf = *(const bf16x8*)&Vt[(dt * 16 + ln) * 72 + ks * 32 + qd * 8];
                o[dt] = __builtin_amdgcn_mfma_f32_16x16x32_bf16(vf, pf, o[dt], 0, 0, 0);
            }
        }
    }

    l += __shfl_xor(l, 16, 64);
    l += __shfl_xor(l, 32, 64);

    size_t pid = (size_t)bh * NCHUNK + cid;
    u16* op = Po + pid * 4096;
    for (int dt = 0; dt < 4; dt++) {
        u16x4 ov;
        ov[0] = f2b(o[dt][0]); ov[1] = f2b(o[dt][1]);
        ov[2] = f2b(o[dt][2]); ov[3] = f2b(o[dt][3]);
        *(u16x4*)&op[(w * 16 + ln) * 64 + dt * 16 + qd * 4] = ov;
    }
    if (qd == 0)
        Plv[pid * 64 + w * 16 + ln] = l;
}

// ---------------- combine partials -> Z bf16 [4096][768] ----------------

__global__ __launch_bounds__(256) void combine(const u16* __restrict__ Po, const float* __restrict__ Plv,
                                               u16* __restrict__ Zb) {
    int qt = blockIdx.x, bh = blockIdx.y;
    int b = bh / NH, h = bh % NH;
    int nc = (qt >> 3) + 1;
    int base;
    if (qt < 8) base = qt;
    else if (qt < 16) base = 8 + (qt - 8) * 2;
    else if (qt < 24) base = 24 + (qt - 16) * 3;
    else base = 48 + (qt - 24) * 4;
    int t = threadIdx.x;
    int q = t >> 2, dseg = (t & 3) * 16;

    float acc[16] = {};
    float lsum = 0.f;
    for (int cc = 0; cc < nc; cc++) {
        size_t pid = (size_t)bh * NCHUNK + base + cc;
        lsum += Plv[pid * 64 + q];
        const u16* op = Po + pid * 4096 + q * 64 + dseg;
        for (int j = 0; j < 2; j++) {
            u16x8 v = *(const u16x8*)(op + j * 8);
            for (int e = 0; e < 8; e++)
                acc[j * 8 + e] += b2f(v[e]);
        }
    }
    float inv = 1.0f / lsum;
    u16* Zp = Zb + ((size_t)b * SLEN + qt * 64 + q) * DM + h * DH + dseg;
    u16x8 ov;
    for (int j = 0; j < 2; j++) {
        for (int e = 0; e < 8; e++) ov[e] = f2b(acc[j * 8 + e] * inv);
        *(u16x8*)(Zp + j * 8) = ov;
    }
}

// ---------------- output projection (64x96 tile, global_load_lds staging) ----------------
// grid (8, 64) = 512 blocks = 2.0 blocks/CU exact.

__global__ __launch_bounds__(256) void gemm_proj(const u16* __restrict__ A, const u16* __restrict__ Bt,
                                                 const float* __restrict__ bO, float* __restrict__ out) {
    __shared__ u16 Al[64 * 64];
    __shared__ u16 Bl[96 * 64];
    int t = threadIdx.x;
    int n0 = blockIdx.x * 96, m0 = blockIdx.y * 64;
    int lane = t & 63, w = t >> 6;
    int ln = lane & 15, qd = lane >> 4;
    int wr = (w & 1) * 32, wc = (w >> 1) * 48;
    int srow = lane >> 3, slot = lane & 7;
    f32x4 acc[2][3] = {};

    for (int kt = 0; kt < DM / 64; kt++) {
        __syncthreads();
        for (int j = 0; j < 2; j++) {
            int r = w * 16 + j * 8 + srow;
            int gc = slot ^ (r & 7);
            gload16(A + (size_t)(m0 + r) * DM + kt * 64 + gc * 8, &Al[(w * 16 + j * 8) * 64]);
        }
        for (int j = 0; j < 3; j++) {
            int r = w * 24 + j * 8 + srow;
            int gc = slot ^ (r & 7);
            gload16(Bt + (size_t)(n0 + r) * DM + kt * 64 + gc * 8, &Bl[(w * 24 + j * 8) * 64]);
        }
        __syncthreads();
        for (int ks = 0; ks < 2; ks++) {
            int sl = ((ks * 4 + qd) ^ (ln & 7)) * 8;
            bf16x8 af[2], bfr[3];
            for (int rt = 0; rt < 2; rt++)
                af[rt] = *(const bf16x8*)&Al[(wr + rt * 16 + ln) * 64 + sl];
            for (int ct = 0; ct < 3; ct++)
                bfr[ct] = *(const bf16x8*)&Bl[(wc + ct * 16 + ln) * 64 + sl];
            for (int rt = 0; rt < 2; rt++)
                for (int ct = 0; ct < 3; ct++)
                    acc[rt][ct] = __builtin_amdgcn_mfma_f32_16x16x32_bf16(af[rt], bfr[ct], acc[rt][ct], 0, 0, 0);
        }
    }
    for (int ct = 0; ct < 3; ct++) {
        int col = n0 + wc + ct * 16 + ln;
        float bv = bO[col];
        for (int rt = 0; rt < 2; rt++) {
            int row = m0 + wr + rt * 16 + qd * 4;
            for (int r = 0; r < 4; r++)
                out[(size_t)(row + r) * DM + col] = acc[rt][ct][r] + bv;
        }
    }
}

// ---------------- launch ----------------

extern "C" void kernel_launch(void* const* d_in, const int* in_sizes, int n_in,
                              void* d_out, int out_size, void* d_ws, size_t ws_size,
                              hipStream_t stream) {
    const float* x  = (const float*)d_in[0];
    const float* WQ = (const float*)d_in[1];
    const float* bQ = (const float*)d_in[2];
    const float* WK = (const float*)d_in[3];
    const float* bK = (const float*)d_in[4];
    const float* WV = (const float*)d_in[5];
    const float* bV = (const float*)d_in[6];
    const float* WO = (const float*)d_in[7];
    const float* bO = (const float*)d_in[8];
    float* out = (float*)d_out;

    u16* xb   = (u16*)d_ws;                        // [4096][768]
    u16* wqkv = xb + (size_t)ROWS * DM;            // [2304][768]
    u16* wo   = wqkv + (size_t)NQKV * DM;          // [768][768]
    u16* Qb   = wo + (size_t)DM * DM;
    size_t hsz = (size_t)BATCH * NH * SLEN * DH;
    u16* Kb   = Qb + hsz;
    u16* Vb   = Kb + hsz;                          // V^T [b,h,d,s]
    u16* Zb   = Vb + hsz;                          // [4096][768]
    u16* Po   = Zb + (size_t)ROWS * DM;            // partials o: [24*80][64][64] bf16
    float* Pl = (float*)(Po + (size_t)BATCH * NH * NCHUNK * 4096);

    pack_x<<<ROWS * DM / 2048, 256, 0, stream>>>(x, xb);
    pack_wqkv<<<dim3(12, 12, 3), 256, 0, stream>>>(WQ, WK, WV, wqkv);
    pack_wo<<<dim3(12, 12), 256, 0, stream>>>(WO, wo);
    gemm_qkv<<<dim3(NQKV / 128, ROWS / 128), 256, 0, stream>>>(xb, wqkv, bQ, bK, bV, Qb, Kb, Vb);
    attn<<<dim3(NCHUNK, BATCH * NH), 256, 0, stream>>>(Qb, Kb, Vb, Po, Pl);
    combine<<<dim3(SLEN / 64, BATCH * NH), 256, 0, stream>>>(Po, Pl, Zb);
    gemm_proj<<<dim3(DM / 96, ROWS / 64), 256, 0, stream>>>(Zb, wo, bO, out);
}